// Round 1
// baseline (1219.736 us; speedup 1.0000x reference)
//
#include <hip/hip_runtime.h>
#include <hip/hip_bf16.h>

// Problem constants
#define B_    32
#define IN_C  8
#define OUT_C 8
#define KK    3
#define MC    32
#define HH_   512
#define WW_   512

// ---------------------------------------------------------------------------
// Kernel A: hypernetwork. One block of 1024 threads computes:
//   m1[b][c] = leaky( sum_j q[b][j]*wm1[c][j] + bm1[c] )         (j over 64)
//   m2[b][c] = leaky( sum_k m1[b][k]*wm2[c][k] + bm2[c] )
//   F[b][(i*9 + kh*3 + kw)*8 + o] = sum_c m2[b][c]*wt[c][(o*8+i)*9+kh*3+kw] + bt[o*8+i]
//   bS[b][o] = sum_c m2[b][c]*wb[o][c] + bb[o]
// F layout: [b][i][kh][kw][o]  (o contiguous)
// ---------------------------------------------------------------------------
__global__ __launch_bounds__(1024) void manifold_kernel(
    const float* __restrict__ q, const float* __restrict__ wm1,
    const float* __restrict__ bm1, const float* __restrict__ wm2,
    const float* __restrict__ bm2, const float* __restrict__ wt,
    const float* __restrict__ bt, const float* __restrict__ wb,
    const float* __restrict__ bb, float* __restrict__ F,
    float* __restrict__ bS)
{
    __shared__ float m1[B_][MC];
    __shared__ float m2[B_][MC];
    int t = threadIdx.x;            // 0..1023
    int b = t >> 5;                 // 0..31
    int c = t & 31;                 // 0..31

    // ---- conv1: full 8x8 contraction
    float s = 0.f;
    #pragma unroll 8
    for (int j = 0; j < 64; ++j)
        s += q[b * 64 + j] * wm1[c * 64 + j];
    s += bm1[c];
    s = (s > 0.f) ? s : 0.01f * s;
    m1[b][c] = s;
    __syncthreads();

    // ---- conv2 (1x1): m2 = m1 @ wm2.T
    float s2 = 0.f;
    #pragma unroll
    for (int k = 0; k < 32; ++k)
        s2 += m1[b][k] * wm2[c * 32 + k];
    s2 += bm2[c];
    s2 = (s2 > 0.f) ? s2 : 0.01f * s2;
    m2[b][c] = s2;
    __syncthreads();

    // ---- weight transform: 32*576 = 18432 filter values
    for (int idx = t; idx < B_ * 576; idx += 1024) {
        int bb_ = idx / 576;
        int rem = idx - bb_ * 576;      // (i*9 + kh*3 + kw)*8 + o
        int o   = rem & 7;
        int tap = rem >> 3;             // i*9 + kh*3 + kw
        int i   = tap / 9;
        int kk  = tap - i * 9;          // kh*3 + kw
        int widx = (o * IN_C + i) * 9 + kk;
        float acc = bt[o * IN_C + i];
        #pragma unroll
        for (int cc = 0; cc < 32; ++cc)
            acc += m2[bb_][cc] * wt[cc * 576 + widx];
        F[idx] = acc;
    }

    // ---- bias transform: 32*8 = 256 values
    if (t < B_ * OUT_C) {
        int bb2 = t >> 3;
        int o   = t & 7;
        float acc = bb[o];
        #pragma unroll
        for (int cc = 0; cc < 32; ++cc)
            acc += m2[bb2][cc] * wb[o * 32 + cc];
        bS[t] = acc;
    }
}

// ---------------------------------------------------------------------------
// Kernel B: per-sample 3x3 conv, stride 1, pad 1.
// Thread = 4 consecutive output pixels (float4 store) x all 8 out channels.
// Block 256 threads = tile 64 wide x 16 tall. Grid (8, 32, 32).
// x read from global (L1/L2 cached); filters via block-uniform addresses
// (should scalarize to s_load / SGPR broadcast).
// ---------------------------------------------------------------------------
__global__ __launch_bounds__(256) void conv_main_kernel(
    const float* __restrict__ x, const float* __restrict__ F,
    const float* __restrict__ bS, float* __restrict__ y)
{
    const int b  = blockIdx.z;
    const int w0 = blockIdx.x * 64;
    const int h0 = blockIdx.y * 16;
    const int tx = threadIdx.x & 15;   // 0..15 -> 4-px group
    const int ty = threadIdx.x >> 4;   // 0..15 -> row
    const int h  = h0 + ty;
    const int w  = w0 + tx * 4;

    const float* __restrict__ Fb = F + b * 576;
    const float* __restrict__ xb = x + (size_t)b * IN_C * HH_ * WW_;

    float acc[OUT_C][4];
    #pragma unroll
    for (int o = 0; o < OUT_C; ++o) {
        float bv = bS[b * OUT_C + o];
        #pragma unroll
        for (int p = 0; p < 4; ++p) acc[o][p] = bv;
    }

    #pragma unroll
    for (int i = 0; i < IN_C; ++i) {
        const float* __restrict__ xc = xb + (size_t)i * HH_ * WW_;
        #pragma unroll
        for (int r = 0; r < KK; ++r) {
            const int hh = h + r - 1;
            const bool hok = (unsigned)hh < (unsigned)HH_;
            float xv[6];
            #pragma unroll
            for (int c = 0; c < 6; ++c) {
                const int ww = w + c - 1;
                const bool ok = hok && ((unsigned)ww < (unsigned)WW_);
                xv[c] = ok ? xc[hh * WW_ + ww] : 0.f;
            }
            #pragma unroll
            for (int kw = 0; kw < KK; ++kw) {
                #pragma unroll
                for (int o = 0; o < OUT_C; ++o) {
                    // block-uniform address -> expect s_load (SGPR operand)
                    const float f = Fb[(i * 9 + r * 3 + kw) * 8 + o];
                    #pragma unroll
                    for (int p = 0; p < 4; ++p)
                        acc[o][p] += xv[kw + p] * f;
                }
            }
        }
    }

    // coalesced float4 stores, one per out channel
    #pragma unroll
    for (int o = 0; o < OUT_C; ++o) {
        float4 v = make_float4(acc[o][0], acc[o][1], acc[o][2], acc[o][3]);
        float* yp = y + (((size_t)b * OUT_C + o) * HH_ + h) * WW_ + w;
        *reinterpret_cast<float4*>(yp) = v;
    }
}

// ---------------------------------------------------------------------------
extern "C" void kernel_launch(void* const* d_in, const int* in_sizes, int n_in,
                              void* d_out, int out_size, void* d_ws, size_t ws_size,
                              hipStream_t stream)
{
    const float* q   = (const float*)d_in[0];
    const float* x   = (const float*)d_in[1];
    const float* wm1 = (const float*)d_in[2];
    const float* bm1 = (const float*)d_in[3];
    const float* wm2 = (const float*)d_in[4];
    const float* bm2 = (const float*)d_in[5];
    const float* wt  = (const float*)d_in[6];
    const float* bt  = (const float*)d_in[7];
    const float* wb  = (const float*)d_in[8];
    const float* bb  = (const float*)d_in[9];
    float* out = (float*)d_out;

    float* F  = (float*)d_ws;                  // 32*576 = 18432 floats
    float* bS = F + B_ * 576;                  // 32*8   = 256 floats

    manifold_kernel<<<1, 1024, 0, stream>>>(q, wm1, bm1, wm2, bm2, wt, bt, wb, bb, F, bS);

    dim3 grid(WW_ / 64, HH_ / 16, B_);
    conv_main_kernel<<<grid, 256, 0, stream>>>(x, F, bS, out);
}

// Round 2
// 553.675 us; speedup vs baseline: 2.2030x; 2.2030x over previous
//
#include <hip/hip_runtime.h>
#include <hip/hip_bf16.h>

// Problem constants
#define B_    32
#define IN_C  8
#define OUT_C 8
#define KK    3
#define MC    32
#define HH_   512
#define WW_   512

// ---------------------------------------------------------------------------
// Kernel A: hypernetwork, one block per batch sample b (32 blocks x 576 thr).
//   m1[c] = leaky( sum_j q[b][j]*wm1[c][j] + bm1[c] )   (j over 64)
//   m2[c] = leaky( sum_k m1[k]*wm2[c][k] + bm2[c] )
//   F[b][tap*8+o] = sum_c m2[c]*wt[c][(o*8+i)*9+kk] + bt[o*8+i],  tap=i*9+kk
//   bS[b][o] = sum_c m2[c]*wb[o][c] + bb[o]
// F layout: [b][i][kh][kw][o]  (o contiguous) -- matches conv kernel.
// ---------------------------------------------------------------------------
__global__ __launch_bounds__(576) void manifold_kernel(
    const float* __restrict__ q, const float* __restrict__ wm1,
    const float* __restrict__ bm1, const float* __restrict__ wm2,
    const float* __restrict__ bm2, const float* __restrict__ wt,
    const float* __restrict__ bt, const float* __restrict__ wb,
    const float* __restrict__ bb, float* __restrict__ F,
    float* __restrict__ bS)
{
    __shared__ float m1s[MC];
    __shared__ float m2s[MC];
    const int b = blockIdx.x;
    const int t = threadIdx.x;

    if (t < MC) {
        float s = 0.f;
        #pragma unroll 8
        for (int j = 0; j < 64; ++j)
            s += q[b * 64 + j] * wm1[t * 64 + j];
        s += bm1[t];
        m1s[t] = (s > 0.f) ? s : 0.01f * s;
    }
    __syncthreads();
    if (t < MC) {
        float s2 = 0.f;
        #pragma unroll
        for (int k = 0; k < MC; ++k)
            s2 += m1s[k] * wm2[t * MC + k];
        s2 += bm2[t];
        m2s[t] = (s2 > 0.f) ? s2 : 0.01f * s2;
    }
    __syncthreads();

    // one thread per filter value: t = tap*8 + o, tap = i*9 + kk
    {
        const int o   = t & 7;
        const int tap = t >> 3;
        const int i   = tap / 9;
        const int kk  = tap - i * 9;
        const int widx = (o * IN_C + i) * 9 + kk;
        float acc = bt[o * IN_C + i];
        #pragma unroll
        for (int cc = 0; cc < MC; ++cc)
            acc += m2s[cc] * wt[cc * 576 + widx];
        F[b * 576 + t] = acc;
    }

    if (t < OUT_C) {
        float acc = bb[t];
        #pragma unroll
        for (int cc = 0; cc < MC; ++cc)
            acc += m2s[cc] * wb[t * MC + cc];
        bS[b * OUT_C + t] = acc;
    }
}

// ---------------------------------------------------------------------------
// Kernel B: per-sample 3x3 conv, stride 1, pad 1, via LDS staging.
// Block = 256 threads -> output tile 64 wide x 16 tall, all 8 out channels.
// x staged in LDS in 2 chunks of 4 input channels; tile incl. halo is
// 18 rows x 72 cols (global cols w0-4 .. w0+67, aligned float4 loads),
// LDS pitch 76 floats. Filters read via block-uniform addresses -> s_load.
// ---------------------------------------------------------------------------
#define PITCH 76

__global__ __launch_bounds__(256, 4) void conv_main_kernel(
    const float* __restrict__ x, const float* __restrict__ F,
    const float* __restrict__ bS, float* __restrict__ y)
{
    __shared__ float buf[4][18][PITCH];   // 4 ch x 18 rows x 76 -> 21888 B

    const int b  = blockIdx.z;
    const int w0 = blockIdx.x * 64;
    const int h0 = blockIdx.y * 16;
    const int tid = threadIdx.x;
    const int tx = tid & 15;            // 0..15 -> 4-px group
    const int ty = tid >> 4;            // 0..15 -> row
    const int h  = h0 + ty;
    const int w  = w0 + tx * 4;

    const float* __restrict__ Fb = F + b * 576;
    const float* __restrict__ xb = x + (size_t)b * IN_C * HH_ * WW_;

    float acc[OUT_C][4];
    #pragma unroll
    for (int o = 0; o < OUT_C; ++o) {
        float bv = bS[b * OUT_C + o];
        #pragma unroll
        for (int p = 0; p < 4; ++p) acc[o][p] = bv;
    }

    #pragma unroll
    for (int c4 = 0; c4 < 2; ++c4) {
        // ---- stage 4 channels: 4 * 18 rows * 18 float4-groups = 1296 loads
        for (int idx = tid; idx < 4 * 18 * 18; idx += 256) {
            int ii  = idx / 324;
            int rem = idx - ii * 324;
            int rr  = rem / 18;
            int g   = rem - rr * 18;
            int hh   = h0 - 1 + rr;
            int gcol = w0 - 4 + 4 * g;
            float4 v = make_float4(0.f, 0.f, 0.f, 0.f);
            if ((unsigned)hh < (unsigned)HH_ && (unsigned)gcol < (unsigned)WW_) {
                const float* src = xb + ((size_t)(c4 * 4 + ii) * HH_ + hh) * WW_ + gcol;
                v = *reinterpret_cast<const float4*>(src);
            }
            *reinterpret_cast<float4*>(&buf[ii][rr][4 * g]) = v;
        }
        __syncthreads();

        // ---- compute 4 channels from LDS
        #pragma unroll
        for (int ii = 0; ii < 4; ++ii) {
            const int i = c4 * 4 + ii;
            #pragma unroll
            for (int r = 0; r < KK; ++r) {
                const int rowr = ty + r;
                float4 xm = *reinterpret_cast<const float4*>(&buf[ii][rowr][4 * tx + 4]);
                float  xl = buf[ii][rowr][4 * tx + 3];
                float  xr = buf[ii][rowr][4 * tx + 8];
                float xv[6] = { xl, xm.x, xm.y, xm.z, xm.w, xr };
                #pragma unroll
                for (int kw = 0; kw < KK; ++kw) {
                    #pragma unroll
                    for (int o = 0; o < OUT_C; ++o) {
                        // block-uniform address -> s_load (SGPR operand)
                        const float f = Fb[(i * 9 + r * 3 + kw) * 8 + o];
                        #pragma unroll
                        for (int p = 0; p < 4; ++p)
                            acc[o][p] += xv[kw + p] * f;
                    }
                }
            }
        }
        __syncthreads();
    }

    // coalesced float4 stores, one per out channel
    #pragma unroll
    for (int o = 0; o < OUT_C; ++o) {
        float4 v = make_float4(acc[o][0], acc[o][1], acc[o][2], acc[o][3]);
        float* yp = y + (((size_t)b * OUT_C + o) * HH_ + h) * WW_ + w;
        *reinterpret_cast<float4*>(yp) = v;
    }
}

// ---------------------------------------------------------------------------
extern "C" void kernel_launch(void* const* d_in, const int* in_sizes, int n_in,
                              void* d_out, int out_size, void* d_ws, size_t ws_size,
                              hipStream_t stream)
{
    const float* q   = (const float*)d_in[0];
    const float* x   = (const float*)d_in[1];
    const float* wm1 = (const float*)d_in[2];
    const float* bm1 = (const float*)d_in[3];
    const float* wm2 = (const float*)d_in[4];
    const float* bm2 = (const float*)d_in[5];
    const float* wt  = (const float*)d_in[6];
    const float* bt  = (const float*)d_in[7];
    const float* wb  = (const float*)d_in[8];
    const float* bb  = (const float*)d_in[9];
    float* out = (float*)d_out;

    float* Fw = (float*)d_ws;                  // 32*576 = 18432 floats
    float* bS = Fw + B_ * 576;                 // 32*8   = 256 floats

    manifold_kernel<<<B_, 576, 0, stream>>>(q, wm1, bm1, wm2, bm2, wt, bt, wb, bb, Fw, bS);

    dim3 grid(WW_ / 64, HH_ / 16, B_);
    conv_main_kernel<<<grid, 256, 0, stream>>>(x, Fw, bS, out);
}